// Round 8
// baseline (123.752 us; speedup 1.0000x reference)
//
#include <hip/hip_runtime.h>
#include <hip/hip_bf16.h>

// Problem constants
#define BB  8
#define CC  256
#define HW  4096      // 64*64
#define CQ  32
#define CV  128
#define MP  1024      // pooled positions (32*32)

// Workspace layout (float offsets). Total 10,092,544 floats = 40.4 MB.
#define XT_OFF  0                      // xt  [B][HW][256] bf16 (position-major x)
#define Y_OFF   4194304                // y   [B][HW][192] bf16 position-major (q 0-31, k 32-63, v 64-191)
#define KT_OFF  (Y_OFF + 3145728)      // kT  [B][MP][32]  bf16
#define VP_OFF  (KT_OFF + 131072)      // vp  [B][CV][MP]  bf16
#define CT_OFF  (VP_OFF + 524288)      // ctx [B][HW][CV]  bf16 position-major

typedef __attribute__((ext_vector_type(8))) short bf16x8;
typedef __attribute__((ext_vector_type(4))) short short4v;
typedef __attribute__((ext_vector_type(4))) float f32x4;

__device__ __forceinline__ short f2b(float f) {   // fp32 -> bf16 bits, RNE
    unsigned u = __float_as_uint(f);
    u += 0x7fffu + ((u >> 16) & 1u);
    return (short)(u >> 16);
}
__device__ __forceinline__ float b2f(short s) {
    return __uint_as_float(((unsigned)(unsigned short)s) << 16);
}

// ---------------------------------------------------------------------------
// Kernel 0: transpose+convert x[b][c][n] fp32 -> xt[b][n][c] bf16.
// ---------------------------------------------------------------------------
__global__ __launch_bounds__(256) void k_xt(
    const float* __restrict__ x, short* __restrict__ xt)
{
    __shared__ float t[64][65];
    const int bid = blockIdx.x;
    const int nt = bid & 63;
    const int ct = (bid >> 6) & 3;
    const int b  = bid >> 8;
    const int c0 = ct * 64, n0 = nt * 64;
    const int tid = threadIdx.x;

    const int col = tid & 63, wrow = (tid >> 6) * 16;
    #pragma unroll
    for (int i = 0; i < 16; ++i) {
        int r = wrow + i;
        t[r][col] = x[((long)(b * CC + c0 + r)) * HW + n0 + col];
    }
    __syncthreads();

    const int n = tid >> 2, cb = (tid & 3) * 16;
    short buf[16];
    #pragma unroll
    for (int j = 0; j < 16; ++j) buf[j] = f2b(t[cb + j][n]);
    short* dst = &xt[((long)(b * HW + n0 + n)) * CC + c0 + cb];
    *(int4*)dst = *(int4*)&buf[0];
    *(int4*)(dst + 8) = *(int4*)&buf[8];
}

// ---------------------------------------------------------------------------
// Kernel 1: qkv conv as bf16 MFMA GEMM -> y_pm[b][n][192] bf16.
// ---------------------------------------------------------------------------
__global__ __launch_bounds__(256) void k_qkv(
    const float* __restrict__ wq, const float* __restrict__ wk,
    const float* __restrict__ wv, const short* __restrict__ xt,
    short* __restrict__ y)
{
    __shared__ short w_lds[96 * 264];
    __shared__ short x_lds[256 * 40];
    const int bid = blockIdx.x;
    const int oc = bid & 1;
    const int nt = (bid >> 1) & 15;
    const int b  = bid >> 5;
    const int o0 = oc * 96, n0 = nt * 256;
    const int tid = threadIdx.x;
    const int lane = tid & 63;
    const int wvid = tid >> 6;
    const int l15 = lane & 15, g = lane >> 4;

    for (int it = 0; it < 24; ++it) {
        int idx = tid + it * 256;
        int ol = idx >> 6, cq = (idx & 63) * 4;
        int o = o0 + ol;
        const float* src = (o < 32) ? &wq[o * 256 + cq]
                         : (o < 64) ? &wk[(o - 32) * 256 + cq]
                                    : &wv[(o - 64) * 256 + cq];
        float4 w = *(const float4*)src;
        short4v p = { f2b(w.x), f2b(w.y), f2b(w.z), f2b(w.w) };
        *(short4v*)&w_lds[ol * 264 + cq] = p;
    }

    f32x4 acc[4][6];
    #pragma unroll
    for (int nf = 0; nf < 4; ++nf)
        #pragma unroll
        for (int of = 0; of < 6; ++of) acc[nf][of] = (f32x4){0.f, 0.f, 0.f, 0.f};

    for (int ks = 0; ks < 8; ++ks) {
        __syncthreads();
        {
            const short* src = &xt[((long)(b * HW + n0 + tid)) * CC + ks * 32];
            int4 v0 = *(const int4*)src;
            int4 v1 = *(const int4*)(src + 8);
            int4 v2 = *(const int4*)(src + 16);
            int4 v3 = *(const int4*)(src + 24);
            short* dst = &x_lds[tid * 40];
            *(int4*)dst = v0; *(int4*)(dst + 8) = v1;
            *(int4*)(dst + 16) = v2; *(int4*)(dst + 24) = v3;
        }
        __syncthreads();

        bf16x8 a[4], bf[6];
        #pragma unroll
        for (int nf = 0; nf < 4; ++nf)
            a[nf] = *(const bf16x8*)&x_lds[(wvid * 64 + nf * 16 + l15) * 40 + 8 * g];
        #pragma unroll
        for (int of = 0; of < 6; ++of)
            bf[of] = *(const bf16x8*)&w_lds[(of * 16 + l15) * 264 + ks * 32 + 8 * g];
        #pragma unroll
        for (int nf = 0; nf < 4; ++nf)
            #pragma unroll
            for (int of = 0; of < 6; ++of)
                acc[nf][of] = __builtin_amdgcn_mfma_f32_16x16x32_bf16(a[nf], bf[of], acc[nf][of], 0, 0, 0);
    }

    #pragma unroll
    for (int nf = 0; nf < 4; ++nf) {
        #pragma unroll
        for (int of = 0; of < 6; ++of) {
            int o = o0 + of * 16 + l15;
            long nb = (long)(b * HW + n0 + wvid * 64 + nf * 16 + 4 * g);
            #pragma unroll
            for (int r = 0; r < 4; ++r)
                y[(nb + r) * 192 + o] = f2b(acc[nf][of][r]);
        }
    }
}

// ---------------------------------------------------------------------------
// Kernel 2: 2x2 maxpool from y_pm. kT[b][m][32]; vp[b][c][m] via LDS transpose.
// ---------------------------------------------------------------------------
__global__ __launch_bounds__(256) void k_pool(
    const short* __restrict__ y, short* __restrict__ kT, short* __restrict__ vp)
{
    __shared__ short t[64 * 136];
    const int bid = blockIdx.x;
    const int mt = bid & 15;
    const int b  = bid >> 4;
    const int m0 = mt * 64;
    const int tid = threadIdx.x;

    {
        int ml = tid >> 2, ci = (tid & 3) * 8;
        int pp = m0 + ml;
        int ph = pp >> 5, pw = pp & 31;
        const short* src = &y[((long)(b * HW) + ph * 128 + pw * 2) * 192 + 32 + ci];
        int4 s0 = *(const int4*)src;
        int4 s1 = *(const int4*)(src + 192);
        int4 s2 = *(const int4*)(src + 12288);
        int4 s3 = *(const int4*)(src + 12480);
        const short *a = (const short*)&s0, *bb = (const short*)&s1,
                    *c = (const short*)&s2, *d = (const short*)&s3;
        short o8[8];
        #pragma unroll
        for (int j = 0; j < 8; ++j)
            o8[j] = f2b(fmaxf(fmaxf(b2f(a[j]), b2f(bb[j])), fmaxf(b2f(c[j]), b2f(d[j]))));
        *(int4*)&kT[((long)(b * MP + pp)) * CQ + ci] = *(int4*)o8;
    }
    #pragma unroll
    for (int jj = 0; jj < 4; ++jj) {
        int idx = tid + jj * 256;
        int ml = idx >> 4, ci = (idx & 15) * 8;
        int pp = m0 + ml;
        int ph = pp >> 5, pw = pp & 31;
        const short* src = &y[((long)(b * HW) + ph * 128 + pw * 2) * 192 + 64 + ci];
        int4 s0 = *(const int4*)src;
        int4 s1 = *(const int4*)(src + 192);
        int4 s2 = *(const int4*)(src + 12288);
        int4 s3 = *(const int4*)(src + 12480);
        const short *a = (const short*)&s0, *bb = (const short*)&s1,
                    *c = (const short*)&s2, *d = (const short*)&s3;
        short o8[8];
        #pragma unroll
        for (int j = 0; j < 8; ++j)
            o8[j] = f2b(fmaxf(fmaxf(b2f(a[j]), b2f(bb[j])), fmaxf(b2f(c[j]), b2f(d[j]))));
        *(int4*)&t[ml * 136 + ci] = *(int4*)o8;
    }
    __syncthreads();
    {
        int c = tid & 127, mc = (tid >> 7) * 32;
        short buf[32];
        #pragma unroll
        for (int mm = 0; mm < 32; ++mm) buf[mm] = t[(mc + mm) * 136 + c];
        short* dst = &vp[((long)(b * CV + c)) * MP + m0 + mc];
        *(int4*)dst = *(int4*)&buf[0];
        *(int4*)(dst + 8)  = *(int4*)&buf[8];
        *(int4*)(dst + 16) = *(int4*)&buf[16];
        *(int4*)(dst + 24) = *(int4*)&buf[24];
    }
}

// ---------------------------------------------------------------------------
// Kernel 3: MFMA flash attention — R3-verified core, re-tiled for occupancy.
// Per-wave tile shrunk 32->16 queries (si dimension removed verbatim from the
// R3 kernel); 4 waves/block each own an independent 16-query subtile over the
// FULL m range. No cross-wave state, no union, no in-loop barriers, no
// launch-bounds cap. Grid 512 blocks -> 2048 waves (2/SIMD, 2x R3).
// ---------------------------------------------------------------------------
__global__ __launch_bounds__(256) void k_attn(
    const short* __restrict__ y,      // y_pm: q = cols 0..31
    const short* __restrict__ kT,     // [b][1024][32]
    const short* __restrict__ vp,     // [b][128][1024]
    short* __restrict__ ctx)          // [b][4096][128] bf16
{
    __shared__ short p_lds[4][16][40];   // per-wave slice, 5120 B total
    const int tid  = threadIdx.x;
    const int lane = tid & 63;
    const int wid  = tid >> 6;
    const int b    = blockIdx.x >> 6;
    const int q0   = (blockIdx.x & 63) * 64 + wid * 16;
    const int l15  = lane & 15;
    const int g    = lane >> 4;

    // Q B-frag: direct contiguous load from position-major y
    const short* yq = y + (long)b * HW * 192;
    bf16x8 qf = *(const bf16x8*)&yq[(long)(q0 + l15) * 192 + 8 * g];

    float m_run = -INFINITY;
    float l_run = 0.f;
    f32x4 acc[8];
    #pragma unroll
    for (int ct = 0; ct < 8; ++ct)
        acc[ct] = (f32x4){0.f, 0.f, 0.f, 0.f};

    const short* kTb = kT + (long)b * MP * CQ;
    const short* vpb = vp + (long)b * CV * MP;

    for (int t = 0; t < 32; ++t) {
        const int m0 = t * 32;
        bf16x8 ka0 = *(const bf16x8*)&kTb[(m0 + l15) * CQ + 8 * g];
        bf16x8 ka1 = *(const bf16x8*)&kTb[(m0 + 16 + l15) * CQ + 8 * g];
        bf16x8 va[8];
        #pragma unroll
        for (int ct = 0; ct < 8; ++ct)
            va[ct] = *(const bf16x8*)&vpb[(ct * 16 + l15) * MP + m0 + 8 * g];

        f32x4 s0 = (f32x4){0.f, 0.f, 0.f, 0.f};
        f32x4 s1 = (f32x4){0.f, 0.f, 0.f, 0.f};
        s0 = __builtin_amdgcn_mfma_f32_16x16x32_bf16(ka0, qf, s0, 0, 0, 0);
        s1 = __builtin_amdgcn_mfma_f32_16x16x32_bf16(ka1, qf, s1, 0, 0, 0);
        // lane holds S[q=l15][m0 + {4g+r, 16+4g+r}]
        float tmax = fmaxf(fmaxf(fmaxf(s0[0], s0[1]), fmaxf(s0[2], s0[3])),
                           fmaxf(fmaxf(s1[0], s1[1]), fmaxf(s1[2], s1[3])));
        tmax = fmaxf(tmax, __shfl_xor(tmax, 16, 64));
        tmax = fmaxf(tmax, __shfl_xor(tmax, 32, 64));
        float mr = m_run;
        if (!__all(tmax <= mr + 8.0f)) {      // defer-rescale (T13)
            float nm = fmaxf(mr, tmax);
            float alpha = __expf(mr - nm);    // 0 on first tile
            l_run *= alpha;
            #pragma unroll
            for (int r = 0; r < 4; ++r) {
                float ar = __shfl(alpha, 4 * g + r, 64);   // alpha for row q=4g+r
                #pragma unroll
                for (int ct = 0; ct < 8; ++ct) acc[ct][r] *= ar;
            }
            m_run = nm;
            mr = nm;
        }
        float p[8];
        #pragma unroll
        for (int r = 0; r < 4; ++r) { p[r] = __expf(s0[r] - mr); p[4 + r] = __expf(s1[r] - mr); }
        float ts = ((p[0] + p[1]) + (p[2] + p[3])) + ((p[4] + p[5]) + (p[6] + p[7]));
        ts += __shfl_xor(ts, 16, 64);
        ts += __shfl_xor(ts, 32, 64);
        l_run += ts;
        short4v w0 = { f2b(p[0]), f2b(p[1]), f2b(p[2]), f2b(p[3]) };
        short4v w1 = { f2b(p[4]), f2b(p[5]), f2b(p[6]), f2b(p[7]) };
        *(short4v*)&p_lds[wid][l15][4 * g]      = w0;   // m-local 4g+r
        *(short4v*)&p_lds[wid][l15][16 + 4 * g] = w1;   // m-local 16+4g+r

        bf16x8 pf = *(const bf16x8*)&p_lds[wid][l15][8 * g];  // A[q][m]
        #pragma unroll
        for (int ct = 0; ct < 8; ++ct)
            acc[ct] = __builtin_amdgcn_mfma_f32_16x16x32_bf16(pf, va[ct], acc[ct], 0, 0, 0);
    }

    float inv = 1.f / l_run;
    #pragma unroll
    for (int r = 0; r < 4; ++r) {
        float invr = __shfl(inv, 4 * g + r, 64);
        long q = q0 + 4 * g + r;
        short* cb = &ctx[((long)b * HW + q) * CV];
        #pragma unroll
        for (int ct = 0; ct < 8; ++ct)
            cb[ct * 16 + l15] = f2b(acc[ct][r] * invr);
    }
}

// ---------------------------------------------------------------------------
// Kernel 4: out = gamma * wo @ ctx + x as bf16 MFMA.
// ---------------------------------------------------------------------------
__global__ __launch_bounds__(256) void k_out(
    const short* __restrict__ ctx, const float* __restrict__ wo,
    const float* __restrict__ x, const float* __restrict__ gamma,
    float* __restrict__ out)
{
    __shared__ short c_lds[256 * 136];
    __shared__ short w_lds[128 * 136];
    const int bid = blockIdx.x;
    const int oc = bid & 1;
    const int nt = (bid >> 1) & 15;
    const int b  = bid >> 5;
    const int o0 = oc * 128, n0 = nt * 256;
    const int tid = threadIdx.x;
    const int lane = tid & 63;
    const int l15 = lane & 15, g = lane >> 4;

    {
        const short* src = &ctx[((long)(b * HW + n0 + tid)) * CV];
        short* dst = &c_lds[tid * 136];
        #pragma unroll
        for (int j = 0; j < 16; ++j)
            *(int4*)(dst + 8 * j) = *(const int4*)(src + 8 * j);
    }
    for (int it = 0; it < 16; ++it) {
        int idx = tid + it * 256;
        int ol = idx >> 5, cq = (idx & 31) * 4;
        float4 w = *(const float4*)&wo[(o0 + ol) * CV + cq];
        short4v p = { f2b(w.x), f2b(w.y), f2b(w.z), f2b(w.w) };
        *(short4v*)&w_lds[ol * 136 + cq] = p;
    }
    __syncthreads();

    const int wvid = tid >> 6;
    const int ow = (wvid & 1) * 64, nw = (wvid >> 1) * 128;
    f32x4 acc[4][8];
    #pragma unroll
    for (int of = 0; of < 4; ++of)
        #pragma unroll
        for (int nf = 0; nf < 8; ++nf) acc[of][nf] = (f32x4){0.f, 0.f, 0.f, 0.f};

    #pragma unroll
    for (int ks = 0; ks < 4; ++ks) {
        bf16x8 af[4], bf[8];
        #pragma unroll
        for (int of = 0; of < 4; ++of)
            af[of] = *(const bf16x8*)&w_lds[(ow + of * 16 + l15) * 136 + ks * 32 + 8 * g];
        #pragma unroll
        for (int nf = 0; nf < 8; ++nf)
            bf[nf] = *(const bf16x8*)&c_lds[(nw + nf * 16 + l15) * 136 + ks * 32 + 8 * g];
        #pragma unroll
        for (int of = 0; of < 4; ++of)
            #pragma unroll
            for (int nf = 0; nf < 8; ++nf)
                acc[of][nf] = __builtin_amdgcn_mfma_f32_16x16x32_bf16(af[of], bf[nf], acc[of][nf], 0, 0, 0);
    }

    const float gma = gamma[0];
    #pragma unroll
    for (int of = 0; of < 4; ++of) {
        #pragma unroll
        for (int r = 0; r < 4; ++r) {
            int o = o0 + ow + of * 16 + 4 * g + r;
            #pragma unroll
            for (int nf = 0; nf < 8; ++nf) {
                int n = n0 + nw + nf * 16 + l15;
                long idx = (long)(b * CC + o) * HW + n;
                out[idx] = gma * acc[of][nf][r] + x[idx];
            }
        }
    }
}

// ---------------------------------------------------------------------------
extern "C" void kernel_launch(void* const* d_in, const int* in_sizes, int n_in,
                              void* d_out, int out_size, void* d_ws, size_t ws_size,
                              hipStream_t stream) {
    const float* x     = (const float*)d_in[0];
    const float* wq    = (const float*)d_in[1];
    const float* wk    = (const float*)d_in[2];
    const float* wv    = (const float*)d_in[3];
    const float* wo    = (const float*)d_in[4];
    const float* gamma = (const float*)d_in[5];
    float* out = (float*)d_out;
    float* ws  = (float*)d_ws;

    short* xt  = (short*)(ws + XT_OFF);
    short* y   = (short*)(ws + Y_OFF);
    short* kT  = (short*)(ws + KT_OFF);
    short* vp  = (short*)(ws + VP_OFF);
    short* ctx = (short*)(ws + CT_OFF);

    k_xt  <<<dim3(2048), dim3(256), 0, stream>>>(x, xt);
    k_qkv <<<dim3(256),  dim3(256), 0, stream>>>(wq, wk, wv, xt, y);
    k_pool<<<dim3(128),  dim3(256), 0, stream>>>(y, kT, vp);
    k_attn<<<dim3(512),  dim3(256), 0, stream>>>(y, kT, vp, ctx);
    k_out <<<dim3(256),  dim3(256), 0, stream>>>(ctx, wo, x, gamma, out);
}

// Round 10
// 96.544 us; speedup vs baseline: 1.2818x; 1.2818x over previous
//
#include <hip/hip_runtime.h>
#include <hip/hip_bf16.h>

// Problem constants
#define BB  8
#define CC  256
#define HW  4096      // 64*64
#define CQ  32
#define CV  128
#define MP  1024      // pooled positions (32*32)

// Workspace layout (float offsets). Total 10,092,544 floats = 40.4 MB.
#define XT_OFF  0                      // xt  [B][HW][256] bf16 (position-major x)
#define Y_OFF   4194304                // y   [B][HW][192] bf16 position-major (q 0-31, k 32-63, v 64-191)
#define KT_OFF  (Y_OFF + 3145728)      // kT  [B][MP][32]  bf16
#define VP_OFF  (KT_OFF + 131072)      // vp  [B][CV][MP]  bf16
#define CT_OFF  (VP_OFF + 524288)      // ctx [B][HW][CV]  bf16 position-major

typedef __attribute__((ext_vector_type(8))) short bf16x8;
typedef __attribute__((ext_vector_type(4))) short short4v;
typedef __attribute__((ext_vector_type(4))) float f32x4;

__device__ __forceinline__ short f2b(float f) {   // fp32 -> bf16 bits, RNE
    unsigned u = __float_as_uint(f);
    u += 0x7fffu + ((u >> 16) & 1u);
    return (short)(u >> 16);
}
__device__ __forceinline__ float b2f(short s) {
    return __uint_as_float(((unsigned)(unsigned short)s) << 16);
}

// ---------------------------------------------------------------------------
// Kernel 0: transpose+convert x[b][c][n] fp32 -> xt[b][n][c] bf16.
// ---------------------------------------------------------------------------
__global__ __launch_bounds__(256) void k_xt(
    const float* __restrict__ x, short* __restrict__ xt)
{
    __shared__ float t[64][65];
    const int bid = blockIdx.x;
    const int nt = bid & 63;
    const int ct = (bid >> 6) & 3;
    const int b  = bid >> 8;
    const int c0 = ct * 64, n0 = nt * 64;
    const int tid = threadIdx.x;

    const int col = tid & 63, wrow = (tid >> 6) * 16;
    #pragma unroll
    for (int i = 0; i < 16; ++i) {
        int r = wrow + i;
        t[r][col] = x[((long)(b * CC + c0 + r)) * HW + n0 + col];
    }
    __syncthreads();

    const int n = tid >> 2, cb = (tid & 3) * 16;
    short buf[16];
    #pragma unroll
    for (int j = 0; j < 16; ++j) buf[j] = f2b(t[cb + j][n]);
    short* dst = &xt[((long)(b * HW + n0 + n)) * CC + c0 + cb];
    *(int4*)dst = *(int4*)&buf[0];
    *(int4*)(dst + 8) = *(int4*)&buf[8];
}

// ---------------------------------------------------------------------------
// Kernel 1: qkv conv as bf16 MFMA GEMM -> y_pm[b][n][192] bf16.
// ---------------------------------------------------------------------------
__global__ __launch_bounds__(256) void k_qkv(
    const float* __restrict__ wq, const float* __restrict__ wk,
    const float* __restrict__ wv, const short* __restrict__ xt,
    short* __restrict__ y)
{
    __shared__ short w_lds[96 * 264];
    __shared__ short x_lds[256 * 40];
    const int bid = blockIdx.x;
    const int oc = bid & 1;
    const int nt = (bid >> 1) & 15;
    const int b  = bid >> 5;
    const int o0 = oc * 96, n0 = nt * 256;
    const int tid = threadIdx.x;
    const int lane = tid & 63;
    const int wvid = tid >> 6;
    const int l15 = lane & 15, g = lane >> 4;

    for (int it = 0; it < 24; ++it) {
        int idx = tid + it * 256;
        int ol = idx >> 6, cq = (idx & 63) * 4;
        int o = o0 + ol;
        const float* src = (o < 32) ? &wq[o * 256 + cq]
                         : (o < 64) ? &wk[(o - 32) * 256 + cq]
                                    : &wv[(o - 64) * 256 + cq];
        float4 w = *(const float4*)src;
        short4v p = { f2b(w.x), f2b(w.y), f2b(w.z), f2b(w.w) };
        *(short4v*)&w_lds[ol * 264 + cq] = p;
    }

    f32x4 acc[4][6];
    #pragma unroll
    for (int nf = 0; nf < 4; ++nf)
        #pragma unroll
        for (int of = 0; of < 6; ++of) acc[nf][of] = (f32x4){0.f, 0.f, 0.f, 0.f};

    for (int ks = 0; ks < 8; ++ks) {
        __syncthreads();
        {
            const short* src = &xt[((long)(b * HW + n0 + tid)) * CC + ks * 32];
            int4 v0 = *(const int4*)src;
            int4 v1 = *(const int4*)(src + 8);
            int4 v2 = *(const int4*)(src + 16);
            int4 v3 = *(const int4*)(src + 24);
            short* dst = &x_lds[tid * 40];
            *(int4*)dst = v0; *(int4*)(dst + 8) = v1;
            *(int4*)(dst + 16) = v2; *(int4*)(dst + 24) = v3;
        }
        __syncthreads();

        bf16x8 a[4], bf[6];
        #pragma unroll
        for (int nf = 0; nf < 4; ++nf)
            a[nf] = *(const bf16x8*)&x_lds[(wvid * 64 + nf * 16 + l15) * 40 + 8 * g];
        #pragma unroll
        for (int of = 0; of < 6; ++of)
            bf[of] = *(const bf16x8*)&w_lds[(of * 16 + l15) * 264 + ks * 32 + 8 * g];
        #pragma unroll
        for (int nf = 0; nf < 4; ++nf)
            #pragma unroll
            for (int of = 0; of < 6; ++of)
                acc[nf][of] = __builtin_amdgcn_mfma_f32_16x16x32_bf16(a[nf], bf[of], acc[nf][of], 0, 0, 0);
    }

    #pragma unroll
    for (int nf = 0; nf < 4; ++nf) {
        #pragma unroll
        for (int of = 0; of < 6; ++of) {
            int o = o0 + of * 16 + l15;
            long nb = (long)(b * HW + n0 + wvid * 64 + nf * 16 + 4 * g);
            #pragma unroll
            for (int r = 0; r < 4; ++r)
                y[(nb + r) * 192 + o] = f2b(acc[nf][of][r]);
        }
    }
}

// ---------------------------------------------------------------------------
// Kernel 2: 2x2 maxpool from y_pm. kT[b][m][32]; vp[b][c][m] via LDS transpose.
// ---------------------------------------------------------------------------
__global__ __launch_bounds__(256) void k_pool(
    const short* __restrict__ y, short* __restrict__ kT, short* __restrict__ vp)
{
    __shared__ short t[64 * 136];
    const int bid = blockIdx.x;
    const int mt = bid & 15;
    const int b  = bid >> 4;
    const int m0 = mt * 64;
    const int tid = threadIdx.x;

    {
        int ml = tid >> 2, ci = (tid & 3) * 8;
        int pp = m0 + ml;
        int ph = pp >> 5, pw = pp & 31;
        const short* src = &y[((long)(b * HW) + ph * 128 + pw * 2) * 192 + 32 + ci];
        int4 s0 = *(const int4*)src;
        int4 s1 = *(const int4*)(src + 192);
        int4 s2 = *(const int4*)(src + 12288);
        int4 s3 = *(const int4*)(src + 12480);
        const short *a = (const short*)&s0, *bb = (const short*)&s1,
                    *c = (const short*)&s2, *d = (const short*)&s3;
        short o8[8];
        #pragma unroll
        for (int j = 0; j < 8; ++j)
            o8[j] = f2b(fmaxf(fmaxf(b2f(a[j]), b2f(bb[j])), fmaxf(b2f(c[j]), b2f(d[j]))));
        *(int4*)&kT[((long)(b * MP + pp)) * CQ + ci] = *(int4*)o8;
    }
    #pragma unroll
    for (int jj = 0; jj < 4; ++jj) {
        int idx = tid + jj * 256;
        int ml = idx >> 4, ci = (idx & 15) * 8;
        int pp = m0 + ml;
        int ph = pp >> 5, pw = pp & 31;
        const short* src = &y[((long)(b * HW) + ph * 128 + pw * 2) * 192 + 64 + ci];
        int4 s0 = *(const int4*)src;
        int4 s1 = *(const int4*)(src + 192);
        int4 s2 = *(const int4*)(src + 12288);
        int4 s3 = *(const int4*)(src + 12480);
        const short *a = (const short*)&s0, *bb = (const short*)&s1,
                    *c = (const short*)&s2, *d = (const short*)&s3;
        short o8[8];
        #pragma unroll
        for (int j = 0; j < 8; ++j)
            o8[j] = f2b(fmaxf(fmaxf(b2f(a[j]), b2f(bb[j])), fmaxf(b2f(c[j]), b2f(d[j]))));
        *(int4*)&t[ml * 136 + ci] = *(int4*)o8;
    }
    __syncthreads();
    {
        int c = tid & 127, mc = (tid >> 7) * 32;
        short buf[32];
        #pragma unroll
        for (int mm = 0; mm < 32; ++mm) buf[mm] = t[(mc + mm) * 136 + c];
        short* dst = &vp[((long)(b * CV + c)) * MP + m0 + mc];
        *(int4*)dst = *(int4*)&buf[0];
        *(int4*)(dst + 8)  = *(int4*)&buf[8];
        *(int4*)(dst + 16) = *(int4*)&buf[16];
        *(int4*)(dst + 24) = *(int4*)&buf[24];
    }
}

// ---------------------------------------------------------------------------
// Kernel 3: MFMA flash attention — R3-verified structure (128 thr, 2 waves,
// 32 q/wave, full m-range, per-wave p_lds). Softmax state (m_run, l_run) is
// PER-QUERY, held at lane l15 (NOT wave-uniform). Fast path: per-lane tmax8
// check via __all (equivalent predicate to R3's reduced-max check); l_run as
// per-lane partials reduced once after the loop. Rare breach branch does the
// full cross-lane max and fetches per-ROW alpha via __shfl(alpha, 4g+r)
// (R9's bug: applied lane-l15's alpha to row 4g+r directly).
// ---------------------------------------------------------------------------
__global__ __launch_bounds__(128) void k_attn(
    const short* __restrict__ y,      // y_pm: q = cols 0..31
    const short* __restrict__ kT,     // [b][1024][32]
    const short* __restrict__ vp,     // [b][128][1024]
    short* __restrict__ ctx)          // [b][4096][128] bf16
{
    __shared__ short p_lds[2][2][16][40];
    const int tid  = threadIdx.x;
    const int lane = tid & 63;
    const int wid  = tid >> 6;
    const int b    = blockIdx.x >> 6;
    const int q0   = (blockIdx.x & 63) * 64 + wid * 32;
    const int l15  = lane & 15;
    const int g    = lane >> 4;

    // Q B-frags: direct contiguous loads from position-major y
    bf16x8 qf[2];
    const short* yq = y + (long)b * HW * 192;
    #pragma unroll
    for (int si = 0; si < 2; ++si)
        qf[si] = *(const bf16x8*)&yq[(long)(q0 + si * 16 + l15) * 192 + 8 * g];

    float m_run[2] = {-INFINITY, -INFINITY};   // per-query state (q = l15)
    float l_run[2] = {0.f, 0.f};               // per-lane partial sums (q = l15)
    f32x4 acc[2][8];
    #pragma unroll
    for (int si = 0; si < 2; ++si)
        #pragma unroll
        for (int ct = 0; ct < 8; ++ct)
            acc[si][ct] = (f32x4){0.f, 0.f, 0.f, 0.f};

    const short* kTb = kT + (long)b * MP * CQ;
    const short* vpb = vp + (long)b * CV * MP;

    for (int mt = 0; mt < 32; ++mt) {
        const int m0 = mt * 32;
        bf16x8 ka0 = *(const bf16x8*)&kTb[(m0 + l15) * CQ + 8 * g];
        bf16x8 ka1 = *(const bf16x8*)&kTb[(m0 + 16 + l15) * CQ + 8 * g];
        bf16x8 va[8];
        #pragma unroll
        for (int ct = 0; ct < 8; ++ct)
            va[ct] = *(const bf16x8*)&vpb[(ct * 16 + l15) * MP + m0 + 8 * g];

        #pragma unroll
        for (int si = 0; si < 2; ++si) {
            f32x4 s0 = (f32x4){0.f, 0.f, 0.f, 0.f};
            f32x4 s1 = (f32x4){0.f, 0.f, 0.f, 0.f};
            s0 = __builtin_amdgcn_mfma_f32_16x16x32_bf16(ka0, qf[si], s0, 0, 0, 0);
            s1 = __builtin_amdgcn_mfma_f32_16x16x32_bf16(ka1, qf[si], s1, 0, 0, 0);
            // lane holds S[q=l15][m0 + {4g+r, 16+4g+r}]
            float tmax8 = fmaxf(fmaxf(fmaxf(s0[0], s0[1]), fmaxf(s0[2], s0[3])),
                                fmaxf(fmaxf(s1[0], s1[1]), fmaxf(s1[2], s1[3])));
            float mr = m_run[si];
            if (!__all(tmax8 <= mr + 8.0f)) {     // RARE: full max update
                float tmax = fmaxf(tmax8, __shfl_xor(tmax8, 16, 64));
                tmax = fmaxf(tmax, __shfl_xor(tmax, 32, 64));   // per-query max
                float nm    = fmaxf(mr, tmax);    // per-query (q = l15)
                float alpha = __expf(mr - nm);    // per-query; 0 on first tile
                l_run[si] *= alpha;               // partial of q=l15: exact
                #pragma unroll
                for (int r = 0; r < 4; ++r) {
                    float ar = __shfl(alpha, 4 * g + r, 64);   // alpha of row q=4g+r
                    #pragma unroll
                    for (int ct = 0; ct < 8; ++ct) acc[si][ct][r] *= ar;
                }
                m_run[si] = nm;
                mr = nm;
            }
            float p[8];
            #pragma unroll
            for (int r = 0; r < 4; ++r) { p[r] = __expf(s0[r] - mr); p[4 + r] = __expf(s1[r] - mr); }
            l_run[si] += ((p[0] + p[1]) + (p[2] + p[3])) + ((p[4] + p[5]) + (p[6] + p[7]));
            short4v w0 = { f2b(p[0]), f2b(p[1]), f2b(p[2]), f2b(p[3]) };
            short4v w1 = { f2b(p[4]), f2b(p[5]), f2b(p[6]), f2b(p[7]) };
            *(short4v*)&p_lds[wid][si][l15][4 * g]      = w0;   // m-local 4g+r
            *(short4v*)&p_lds[wid][si][l15][16 + 4 * g] = w1;   // m-local 16+4g+r
        }
        #pragma unroll
        for (int si = 0; si < 2; ++si) {
            bf16x8 pf = *(const bf16x8*)&p_lds[wid][si][l15][8 * g];  // A[q][m]
            #pragma unroll
            for (int ct = 0; ct < 8; ++ct)
                acc[si][ct] = __builtin_amdgcn_mfma_f32_16x16x32_bf16(pf, va[ct], acc[si][ct], 0, 0, 0);
        }
    }

    // finalize l partials: lanes {l15, l15+16, l15+32, l15+48} hold disjoint
    // m-subsets of row q=l15 (all rescaled to the same m_run) -> xor-sum.
    #pragma unroll
    for (int si = 0; si < 2; ++si) {
        l_run[si] += __shfl_xor(l_run[si], 16, 64);
        l_run[si] += __shfl_xor(l_run[si], 32, 64);
    }

    #pragma unroll
    for (int si = 0; si < 2; ++si) {
        float inv = 1.f / l_run[si];
        #pragma unroll
        for (int r = 0; r < 4; ++r) {
            float invr = __shfl(inv, 4 * g + r, 64);   // inv of row q=4g+r
            long q = q0 + si * 16 + 4 * g + r;
            short* cb = &ctx[((long)b * HW + q) * CV];
            #pragma unroll
            for (int ct = 0; ct < 8; ++ct)
                cb[ct * 16 + l15] = f2b(acc[si][ct][r] * invr);
        }
    }
}

// ---------------------------------------------------------------------------
// Kernel 4: out = gamma * wo @ ctx + x as bf16 MFMA.
// ---------------------------------------------------------------------------
__global__ __launch_bounds__(256) void k_out(
    const short* __restrict__ ctx, const float* __restrict__ wo,
    const float* __restrict__ x, const float* __restrict__ gamma,
    float* __restrict__ out)
{
    __shared__ short c_lds[256 * 136];
    __shared__ short w_lds[128 * 136];
    const int bid = blockIdx.x;
    const int oc = bid & 1;
    const int nt = (bid >> 1) & 15;
    const int b  = bid >> 5;
    const int o0 = oc * 128, n0 = nt * 256;
    const int tid = threadIdx.x;
    const int lane = tid & 63;
    const int l15 = lane & 15, g = lane >> 4;

    {
        const short* src = &ctx[((long)(b * HW + n0 + tid)) * CV];
        short* dst = &c_lds[tid * 136];
        #pragma unroll
        for (int j = 0; j < 16; ++j)
            *(int4*)(dst + 8 * j) = *(const int4*)(src + 8 * j);
    }
    for (int it = 0; it < 16; ++it) {
        int idx = tid + it * 256;
        int ol = idx >> 5, cq = (idx & 31) * 4;
        float4 w = *(const float4*)&wo[(o0 + ol) * CV + cq];
        short4v p = { f2b(w.x), f2b(w.y), f2b(w.z), f2b(w.w) };
        *(short4v*)&w_lds[ol * 136 + cq] = p;
    }
    __syncthreads();

    const int wvid = tid >> 6;
    const int ow = (wvid & 1) * 64, nw = (wvid >> 1) * 128;
    f32x4 acc[4][8];
    #pragma unroll
    for (int of = 0; of < 4; ++of)
        #pragma unroll
        for (int nf = 0; nf < 8; ++nf) acc[of][nf] = (f32x4){0.f, 0.f, 0.f, 0.f};

    #pragma unroll
    for (int ks = 0; ks < 4; ++ks) {
        bf16x8 af[4], bf[8];
        #pragma unroll
        for (int of = 0; of < 4; ++of)
            af[of] = *(const bf16x8*)&w_lds[(ow + of * 16 + l15) * 136 + ks * 32 + 8 * g];
        #pragma unroll
        for (int nf = 0; nf < 8; ++nf)
            bf[nf] = *(const bf16x8*)&c_lds[(nw + nf * 16 + l15) * 136 + ks * 32 + 8 * g];
        #pragma unroll
        for (int of = 0; of < 4; ++of)
            #pragma unroll
            for (int nf = 0; nf < 8; ++nf)
                acc[of][nf] = __builtin_amdgcn_mfma_f32_16x16x32_bf16(af[of], bf[nf], acc[of][nf], 0, 0, 0);
    }

    const float gma = gamma[0];
    #pragma unroll
    for (int of = 0; of < 4; ++of) {
        #pragma unroll
        for (int r = 0; r < 4; ++r) {
            int o = o0 + ow + of * 16 + 4 * g + r;
            #pragma unroll
            for (int nf = 0; nf < 8; ++nf) {
                int n = n0 + nw + nf * 16 + l15;
                long idx = (long)(b * CC + o) * HW + n;
                out[idx] = gma * acc[of][nf][r] + x[idx];
            }
        }
    }
}

// ---------------------------------------------------------------------------
extern "C" void kernel_launch(void* const* d_in, const int* in_sizes, int n_in,
                              void* d_out, int out_size, void* d_ws, size_t ws_size,
                              hipStream_t stream) {
    const float* x     = (const float*)d_in[0];
    const float* wq    = (const float*)d_in[1];
    const float* wk    = (const float*)d_in[2];
    const float* wv    = (const float*)d_in[3];
    const float* wo    = (const float*)d_in[4];
    const float* gamma = (const float*)d_in[5];
    float* out = (float*)d_out;
    float* ws  = (float*)d_ws;

    short* xt  = (short*)(ws + XT_OFF);
    short* y   = (short*)(ws + Y_OFF);
    short* kT  = (short*)(ws + KT_OFF);
    short* vp  = (short*)(ws + VP_OFF);
    short* ctx = (short*)(ws + CT_OFF);

    k_xt  <<<dim3(2048), dim3(256), 0, stream>>>(x, xt);
    k_qkv <<<dim3(256),  dim3(256), 0, stream>>>(wq, wk, wv, xt, y);
    k_pool<<<dim3(128),  dim3(256), 0, stream>>>(y, kT, vp);
    k_attn<<<dim3(512),  dim3(128), 0, stream>>>(y, kT, vp, ctx);
    k_out <<<dim3(256),  dim3(256), 0, stream>>>(ctx, wo, x, gamma, out);
}

// Round 11
// 96.392 us; speedup vs baseline: 1.2838x; 1.0016x over previous
//
#include <hip/hip_runtime.h>
#include <hip/hip_bf16.h>

// Problem constants
#define BB  8
#define CC  256
#define HW  4096      // 64*64
#define CQ  32
#define CV  128
#define MP  1024      // pooled positions (32*32)

// Workspace layout (float offsets). Total 10,092,544 floats = 40.4 MB (proven).
#define XT_OFF  0                      // xt  [B][HW][256] bf16 (dead after k_qkv)
#define Y_OFF   4194304                // y   [B][HW][192] bf16 position-major
#define KT_OFF  (Y_OFF + 3145728)      // kT  [B][MP][32]  bf16
#define VP_OFF  (KT_OFF + 131072)      // vp  [B][CV][MP]  bf16
#define CT_OFF  (VP_OFF + 524288)      // ctx [B][HW][CV]  bf16
// Attention split-m partials (aliases, live only between k_attn and k_comb):
#define P0_OFF  CT_OFF                 // split-0 partial bf16 [B*HW][CV] (= ctx area)
#define P1_OFF  XT_OFF                 // split-1 partial bf16 [B*HW][CV] (xt dead)
#define ML_OFF  (XT_OFF + 2097152)     // ml[2][B*HW][2] f32 (in xt area after p1)

typedef __attribute__((ext_vector_type(8))) short bf16x8;
typedef __attribute__((ext_vector_type(4))) short short4v;
typedef __attribute__((ext_vector_type(4))) float f32x4;

__device__ __forceinline__ short f2b(float f) {   // fp32 -> bf16 bits, RNE
    unsigned u = __float_as_uint(f);
    u += 0x7fffu + ((u >> 16) & 1u);
    return (short)(u >> 16);
}
__device__ __forceinline__ float b2f(short s) {
    return __uint_as_float(((unsigned)(unsigned short)s) << 16);
}

// ---------------------------------------------------------------------------
// Kernel 0: transpose+convert x[b][c][n] fp32 -> xt[b][n][c] bf16.
// ---------------------------------------------------------------------------
__global__ __launch_bounds__(256) void k_xt(
    const float* __restrict__ x, short* __restrict__ xt)
{
    __shared__ float t[64][65];
    const int bid = blockIdx.x;
    const int nt = bid & 63;
    const int ct = (bid >> 6) & 3;
    const int b  = bid >> 8;
    const int c0 = ct * 64, n0 = nt * 64;
    const int tid = threadIdx.x;

    const int col = tid & 63, wrow = (tid >> 6) * 16;
    #pragma unroll
    for (int i = 0; i < 16; ++i) {
        int r = wrow + i;
        t[r][col] = x[((long)(b * CC + c0 + r)) * HW + n0 + col];
    }
    __syncthreads();

    const int n = tid >> 2, cb = (tid & 3) * 16;
    short buf[16];
    #pragma unroll
    for (int j = 0; j < 16; ++j) buf[j] = f2b(t[cb + j][n]);
    short* dst = &xt[((long)(b * HW + n0 + n)) * CC + c0 + cb];
    *(int4*)dst = *(int4*)&buf[0];
    *(int4*)(dst + 8) = *(int4*)&buf[8];
}

// ---------------------------------------------------------------------------
// Kernel 1: qkv conv as bf16 MFMA GEMM -> y_pm[b][n][192] bf16.
// ---------------------------------------------------------------------------
__global__ __launch_bounds__(256) void k_qkv(
    const float* __restrict__ wq, const float* __restrict__ wk,
    const float* __restrict__ wv, const short* __restrict__ xt,
    short* __restrict__ y)
{
    __shared__ short w_lds[96 * 264];
    __shared__ short x_lds[256 * 40];
    const int bid = blockIdx.x;
    const int oc = bid & 1;
    const int nt = (bid >> 1) & 15;
    const int b  = bid >> 5;
    const int o0 = oc * 96, n0 = nt * 256;
    const int tid = threadIdx.x;
    const int lane = tid & 63;
    const int wvid = tid >> 6;
    const int l15 = lane & 15, g = lane >> 4;

    for (int it = 0; it < 24; ++it) {
        int idx = tid + it * 256;
        int ol = idx >> 6, cq = (idx & 63) * 4;
        int o = o0 + ol;
        const float* src = (o < 32) ? &wq[o * 256 + cq]
                         : (o < 64) ? &wk[(o - 32) * 256 + cq]
                                    : &wv[(o - 64) * 256 + cq];
        float4 w = *(const float4*)src;
        short4v p = { f2b(w.x), f2b(w.y), f2b(w.z), f2b(w.w) };
        *(short4v*)&w_lds[ol * 264 + cq] = p;
    }

    f32x4 acc[4][6];
    #pragma unroll
    for (int nf = 0; nf < 4; ++nf)
        #pragma unroll
        for (int of = 0; of < 6; ++of) acc[nf][of] = (f32x4){0.f, 0.f, 0.f, 0.f};

    for (int ks = 0; ks < 8; ++ks) {
        __syncthreads();
        {
            const short* src = &xt[((long)(b * HW + n0 + tid)) * CC + ks * 32];
            int4 v0 = *(const int4*)src;
            int4 v1 = *(const int4*)(src + 8);
            int4 v2 = *(const int4*)(src + 16);
            int4 v3 = *(const int4*)(src + 24);
            short* dst = &x_lds[tid * 40];
            *(int4*)dst = v0; *(int4*)(dst + 8) = v1;
            *(int4*)(dst + 16) = v2; *(int4*)(dst + 24) = v3;
        }
        __syncthreads();

        bf16x8 a[4], bf[6];
        #pragma unroll
        for (int nf = 0; nf < 4; ++nf)
            a[nf] = *(const bf16x8*)&x_lds[(wvid * 64 + nf * 16 + l15) * 40 + 8 * g];
        #pragma unroll
        for (int of = 0; of < 6; ++of)
            bf[of] = *(const bf16x8*)&w_lds[(of * 16 + l15) * 264 + ks * 32 + 8 * g];
        #pragma unroll
        for (int nf = 0; nf < 4; ++nf)
            #pragma unroll
            for (int of = 0; of < 6; ++of)
                acc[nf][of] = __builtin_amdgcn_mfma_f32_16x16x32_bf16(a[nf], bf[of], acc[nf][of], 0, 0, 0);
    }

    #pragma unroll
    for (int nf = 0; nf < 4; ++nf) {
        #pragma unroll
        for (int of = 0; of < 6; ++of) {
            int o = o0 + of * 16 + l15;
            long nb = (long)(b * HW + n0 + wvid * 64 + nf * 16 + 4 * g);
            #pragma unroll
            for (int r = 0; r < 4; ++r)
                y[(nb + r) * 192 + o] = f2b(acc[nf][of][r]);
        }
    }
}

// ---------------------------------------------------------------------------
// Kernel 2: 2x2 maxpool from y_pm. kT[b][m][32]; vp[b][c][m] via LDS transpose.
// ---------------------------------------------------------------------------
__global__ __launch_bounds__(256) void k_pool(
    const short* __restrict__ y, short* __restrict__ kT, short* __restrict__ vp)
{
    __shared__ short t[64 * 136];
    const int bid = blockIdx.x;
    const int mt = bid & 15;
    const int b  = bid >> 4;
    const int m0 = mt * 64;
    const int tid = threadIdx.x;

    {
        int ml = tid >> 2, ci = (tid & 3) * 8;
        int pp = m0 + ml;
        int ph = pp >> 5, pw = pp & 31;
        const short* src = &y[((long)(b * HW) + ph * 128 + pw * 2) * 192 + 32 + ci];
        int4 s0 = *(const int4*)src;
        int4 s1 = *(const int4*)(src + 192);
        int4 s2 = *(const int4*)(src + 12288);
        int4 s3 = *(const int4*)(src + 12480);
        const short *a = (const short*)&s0, *bb = (const short*)&s1,
                    *c = (const short*)&s2, *d = (const short*)&s3;
        short o8[8];
        #pragma unroll
        for (int j = 0; j < 8; ++j)
            o8[j] = f2b(fmaxf(fmaxf(b2f(a[j]), b2f(bb[j])), fmaxf(b2f(c[j]), b2f(d[j]))));
        *(int4*)&kT[((long)(b * MP + pp)) * CQ + ci] = *(int4*)o8;
    }
    #pragma unroll
    for (int jj = 0; jj < 4; ++jj) {
        int idx = tid + jj * 256;
        int ml = idx >> 4, ci = (idx & 15) * 8;
        int pp = m0 + ml;
        int ph = pp >> 5, pw = pp & 31;
        const short* src = &y[((long)(b * HW) + ph * 128 + pw * 2) * 192 + 64 + ci];
        int4 s0 = *(const int4*)src;
        int4 s1 = *(const int4*)(src + 192);
        int4 s2 = *(const int4*)(src + 12288);
        int4 s3 = *(const int4*)(src + 12480);
        const short *a = (const short*)&s0, *bb = (const short*)&s1,
                    *c = (const short*)&s2, *d = (const short*)&s3;
        short o8[8];
        #pragma unroll
        for (int j = 0; j < 8; ++j)
            o8[j] = f2b(fmaxf(fmaxf(b2f(a[j]), b2f(bb[j])), fmaxf(b2f(c[j]), b2f(d[j]))));
        *(int4*)&t[ml * 136 + ci] = *(int4*)o8;
    }
    __syncthreads();
    {
        int c = tid & 127, mc = (tid >> 7) * 32;
        short buf[32];
        #pragma unroll
        for (int mm = 0; mm < 32; ++mm) buf[mm] = t[(mc + mm) * 136 + c];
        short* dst = &vp[((long)(b * CV + c)) * MP + m0 + mc];
        *(int4*)dst = *(int4*)&buf[0];
        *(int4*)(dst + 8)  = *(int4*)&buf[8];
        *(int4*)(dst + 16) = *(int4*)&buf[16];
        *(int4*)(dst + 24) = *(int4*)&buf[24];
    }
}

// ---------------------------------------------------------------------------
// Kernel 3: MFMA flash attention, GRID-LEVEL split-m x2. R10-verified body;
// split s (from blockIdx) owns m in [512s, 512s+512) and writes a normalized
// bf16 partial (p0/p1, disjoint buffers) plus per-query (m,l) to ml[]. No
// cross-block or cross-wave coupling. 1024 blocks x 2 waves = 2048 waves.
// ---------------------------------------------------------------------------
__global__ __launch_bounds__(128) void k_attn(
    const short* __restrict__ y,      // y_pm: q = cols 0..31
    const short* __restrict__ kT,     // [b][1024][32]
    const short* __restrict__ vp,     // [b][128][1024]
    short* __restrict__ p0,           // [B*HW][CV] bf16 split-0 partial
    short* __restrict__ p1,           // [B*HW][CV] bf16 split-1 partial
    float* __restrict__ ml)           // [2][B*HW][2] f32 (m, l)
{
    __shared__ short p_lds[2][2][16][40];
    const int tid   = threadIdx.x;
    const int lane  = tid & 63;
    const int wid   = tid >> 6;
    const int split = blockIdx.x >> 9;
    const int rem   = blockIdx.x & 511;
    const int b     = rem >> 6;
    const int q0    = (rem & 63) * 64 + wid * 32;
    const int l15   = lane & 15;
    const int g     = lane >> 4;

    // Q B-frags: direct contiguous loads from position-major y
    bf16x8 qf[2];
    const short* yq = y + (long)b * HW * 192;
    #pragma unroll
    for (int si = 0; si < 2; ++si)
        qf[si] = *(const bf16x8*)&yq[(long)(q0 + si * 16 + l15) * 192 + 8 * g];

    float m_run[2] = {-INFINITY, -INFINITY};   // per-query state (q = l15)
    float l_run[2] = {0.f, 0.f};               // per-lane partial sums (q = l15)
    f32x4 acc[2][8];
    #pragma unroll
    for (int si = 0; si < 2; ++si)
        #pragma unroll
        for (int ct = 0; ct < 8; ++ct)
            acc[si][ct] = (f32x4){0.f, 0.f, 0.f, 0.f};

    const short* kTb = kT + (long)b * MP * CQ;
    const short* vpb = vp + (long)b * CV * MP;

    for (int mt = 0; mt < 16; ++mt) {
        const int m0 = split * 512 + mt * 32;
        bf16x8 ka0 = *(const bf16x8*)&kTb[(m0 + l15) * CQ + 8 * g];
        bf16x8 ka1 = *(const bf16x8*)&kTb[(m0 + 16 + l15) * CQ + 8 * g];
        bf16x8 va[8];
        #pragma unroll
        for (int ct = 0; ct < 8; ++ct)
            va[ct] = *(const bf16x8*)&vpb[(ct * 16 + l15) * MP + m0 + 8 * g];

        #pragma unroll
        for (int si = 0; si < 2; ++si) {
            f32x4 s0 = (f32x4){0.f, 0.f, 0.f, 0.f};
            f32x4 s1 = (f32x4){0.f, 0.f, 0.f, 0.f};
            s0 = __builtin_amdgcn_mfma_f32_16x16x32_bf16(ka0, qf[si], s0, 0, 0, 0);
            s1 = __builtin_amdgcn_mfma_f32_16x16x32_bf16(ka1, qf[si], s1, 0, 0, 0);
            // lane holds S[q=l15][m0 + {4g+r, 16+4g+r}]
            float tmax8 = fmaxf(fmaxf(fmaxf(s0[0], s0[1]), fmaxf(s0[2], s0[3])),
                                fmaxf(fmaxf(s1[0], s1[1]), fmaxf(s1[2], s1[3])));
            float mr = m_run[si];
            if (!__all(tmax8 <= mr + 8.0f)) {     // RARE: full max update
                float tmax = fmaxf(tmax8, __shfl_xor(tmax8, 16, 64));
                tmax = fmaxf(tmax, __shfl_xor(tmax, 32, 64));   // per-query max
                float nm    = fmaxf(mr, tmax);    // per-query (q = l15)
                float alpha = __expf(mr - nm);    // per-query; 0 on first tile
                l_run[si] *= alpha;               // partial of q=l15: exact
                #pragma unroll
                for (int r = 0; r < 4; ++r) {
                    float ar = __shfl(alpha, 4 * g + r, 64);   // alpha of row q=4g+r
                    #pragma unroll
                    for (int ct = 0; ct < 8; ++ct) acc[si][ct][r] *= ar;
                }
                m_run[si] = nm;
                mr = nm;
            }
            float p[8];
            #pragma unroll
            for (int r = 0; r < 4; ++r) { p[r] = __expf(s0[r] - mr); p[4 + r] = __expf(s1[r] - mr); }
            l_run[si] += ((p[0] + p[1]) + (p[2] + p[3])) + ((p[4] + p[5]) + (p[6] + p[7]));
            short4v w0 = { f2b(p[0]), f2b(p[1]), f2b(p[2]), f2b(p[3]) };
            short4v w1 = { f2b(p[4]), f2b(p[5]), f2b(p[6]), f2b(p[7]) };
            *(short4v*)&p_lds[wid][si][l15][4 * g]      = w0;   // m-local 4g+r
            *(short4v*)&p_lds[wid][si][l15][16 + 4 * g] = w1;   // m-local 16+4g+r
        }
        #pragma unroll
        for (int si = 0; si < 2; ++si) {
            bf16x8 pf = *(const bf16x8*)&p_lds[wid][si][l15][8 * g];  // A[q][m]
            #pragma unroll
            for (int ct = 0; ct < 8; ++ct)
                acc[si][ct] = __builtin_amdgcn_mfma_f32_16x16x32_bf16(pf, va[ct], acc[si][ct], 0, 0, 0);
        }
    }

    // finalize l partials: lanes {l15, l15+16, l15+32, l15+48} hold disjoint
    // m-subsets of row q=l15 (all rescaled to the same m_run) -> xor-sum.
    #pragma unroll
    for (int si = 0; si < 2; ++si) {
        l_run[si] += __shfl_xor(l_run[si], 16, 64);
        l_run[si] += __shfl_xor(l_run[si], 32, 64);
    }

    short* pp = split ? p1 : p0;
    #pragma unroll
    for (int si = 0; si < 2; ++si) {
        float inv = 1.f / l_run[si];
        #pragma unroll
        for (int r = 0; r < 4; ++r) {
            float invr = __shfl(inv, 4 * g + r, 64);   // inv of row q=4g+r
            long q = q0 + si * 16 + 4 * g + r;
            short* cb = &pp[((long)b * HW + q) * CV];
            #pragma unroll
            for (int ct = 0; ct < 8; ++ct)
                cb[ct * 16 + l15] = f2b(acc[si][ct][r] * invr);
        }
    }
    // (m, l) for q = lane (lanes 0..15; m_run/l_run valid there for q=l15=lane)
    if (lane < 16) {
        #pragma unroll
        for (int si = 0; si < 2; ++si) {
            long row = (long)(split * BB + b) * HW + q0 + si * 16 + lane;
            ml[row * 2]     = m_run[si];
            ml[row * 2 + 1] = l_run[si];
        }
    }
}

// ---------------------------------------------------------------------------
// Kernel 3b: combine the two split-m partials (exact flash merge), in place
// over the ctx area (ctx == p0; same-thread read-then-write).
// ---------------------------------------------------------------------------
__global__ __launch_bounds__(256) void k_comb(
    const short* __restrict__ p0, const short* __restrict__ p1,
    const float* __restrict__ ml, short* __restrict__ ctx)
{
    const long idx = (long)blockIdx.x * 256 + threadIdx.x;   // 524288 threads
    const long row = idx >> 4;
    const int  c0  = (int)(idx & 15) * 8;
    const float m0 = ml[row * 2],                      l0 = ml[row * 2 + 1];
    const float m1 = ml[((long)BB * HW + row) * 2],    l1 = ml[((long)BB * HW + row) * 2 + 1];
    const float M  = fmaxf(m0, m1);
    float w0 = l0 * __expf(m0 - M);
    float w1 = l1 * __expf(m1 - M);
    const float inv = 1.f / (w0 + w1);
    w0 *= inv; w1 *= inv;
    int4 a4 = *(const int4*)&p0[row * CV + c0];
    int4 b4 = *(const int4*)&p1[row * CV + c0];
    const short* as = (const short*)&a4;
    const short* bs = (const short*)&b4;
    short o8[8];
    #pragma unroll
    for (int j = 0; j < 8; ++j)
        o8[j] = f2b(w0 * b2f(as[j]) + w1 * b2f(bs[j]));
    *(int4*)&ctx[row * CV + c0] = *(int4*)o8;
}

// ---------------------------------------------------------------------------
// Kernel 4: out = gamma * wo @ ctx + x as bf16 MFMA.
// ---------------------------------------------------------------------------
__global__ __launch_bounds__(256) void k_out(
    const short* __restrict__ ctx, const float* __restrict__ wo,
    const float* __restrict__ x, const float* __restrict__ gamma,
    float* __restrict__ out)
{
    __shared__ short c_lds[256 * 136];
    __shared__ short w_lds[128 * 136];
    const int bid = blockIdx.x;
    const int oc = bid & 1;
    const int nt = (bid >> 1) & 15;
    const int b  = bid >> 5;
    const int o0 = oc * 128, n0 = nt * 256;
    const int tid = threadIdx.x;
    const int lane = tid & 63;
    const int l15 = lane & 15, g = lane >> 4;

    {
        const short* src = &ctx[((long)(b * HW + n0 + tid)) * CV];
        short* dst = &c_lds[tid * 136];
        #pragma unroll
        for (int j = 0; j < 16; ++j)
            *(int4*)(dst + 8 * j) = *(const int4*)(src + 8 * j);
    }
    for (int it = 0; it < 16; ++it) {
        int idx = tid + it * 256;
        int ol = idx >> 5, cq = (idx & 31) * 4;
        float4 w = *(const float4*)&wo[(o0 + ol) * CV + cq];
        short4v p = { f2b(w.x), f2b(w.y), f2b(w.z), f2b(w.w) };
        *(short4v*)&w_lds[ol * 136 + cq] = p;
    }
    __syncthreads();

    const int wvid = tid >> 6;
    const int ow = (wvid & 1) * 64, nw = (wvid >> 1) * 128;
    f32x4 acc[4][8];
    #pragma unroll
    for (int of = 0; of < 4; ++of)
        #pragma unroll
        for (int nf = 0; nf < 8; ++nf) acc[of][nf] = (f32x4){0.f, 0.f, 0.f, 0.f};

    #pragma unroll
    for (int ks = 0; ks < 4; ++ks) {
        bf16x8 af[4], bf[8];
        #pragma unroll
        for (int of = 0; of < 4; ++of)
            af[of] = *(const bf16x8*)&w_lds[(ow + of * 16 + l15) * 136 + ks * 32 + 8 * g];
        #pragma unroll
        for (int nf = 0; nf < 8; ++nf)
            bf[nf] = *(const bf16x8*)&c_lds[(nw + nf * 16 + l15) * 136 + ks * 32 + 8 * g];
        #pragma unroll
        for (int of = 0; of < 4; ++of)
            #pragma unroll
            for (int nf = 0; nf < 8; ++nf)
                acc[of][nf] = __builtin_amdgcn_mfma_f32_16x16x32_bf16(af[of], bf[nf], acc[of][nf], 0, 0, 0);
    }

    const float gma = gamma[0];
    #pragma unroll
    for (int of = 0; of < 4; ++of) {
        #pragma unroll
        for (int r = 0; r < 4; ++r) {
            int o = o0 + ow + of * 16 + 4 * g + r;
            #pragma unroll
            for (int nf = 0; nf < 8; ++nf) {
                int n = n0 + nw + nf * 16 + l15;
                long idx = (long)(b * CC + o) * HW + n;
                out[idx] = gma * acc[of][nf][r] + x[idx];
            }
        }
    }
}

// ---------------------------------------------------------------------------
extern "C" void kernel_launch(void* const* d_in, const int* in_sizes, int n_in,
                              void* d_out, int out_size, void* d_ws, size_t ws_size,
                              hipStream_t stream) {
    const float* x     = (const float*)d_in[0];
    const float* wq    = (const float*)d_in[1];
    const float* wk    = (const float*)d_in[2];
    const float* wv    = (const float*)d_in[3];
    const float* wo    = (const float*)d_in[4];
    const float* gamma = (const float*)d_in[5];
    float* out = (float*)d_out;
    float* ws  = (float*)d_ws;

    short* xt  = (short*)(ws + XT_OFF);
    short* y   = (short*)(ws + Y_OFF);
    short* kT  = (short*)(ws + KT_OFF);
    short* vp  = (short*)(ws + VP_OFF);
    short* ctx = (short*)(ws + CT_OFF);
    short* p0  = (short*)(ws + P0_OFF);
    short* p1  = (short*)(ws + P1_OFF);
    float* mlb = ws + ML_OFF;

    k_xt  <<<dim3(2048), dim3(256), 0, stream>>>(x, xt);
    k_qkv <<<dim3(256),  dim3(256), 0, stream>>>(wq, wk, wv, xt, y);
    k_pool<<<dim3(128),  dim3(256), 0, stream>>>(y, kT, vp);
    k_attn<<<dim3(1024), dim3(128), 0, stream>>>(y, kT, vp, p0, p1, mlb);
    k_comb<<<dim3(2048), dim3(256), 0, stream>>>(p0, p1, mlb, ctx);
    k_out <<<dim3(256),  dim3(256), 0, stream>>>(ctx, wo, x, gamma, out);
}